// Round 5
// baseline (104.033 us; speedup 1.0000x reference)
//
#include <hip/hip_runtime.h>

// Conv2D per-batch 3x3x32 valid conv, int32 in (values are int8-range),
// TFLite requant -> int8 (harness stores integer outputs as int32).
// B=64, H_IN=W_IN=226, CIN=32, H_OUT=W_OUT=224.
//
// dot4-packed (v_dot4_i32_i8) + 3-slot packed row window to get VGPR <= 73
// so all 1792 blocks are co-resident (7 blocks/CU = 7 waves/SIMD via
// __launch_bounds__(256,7)) -- kills the 2-round drain tail.

typedef int int4v __attribute__((ext_vector_type(4)));
typedef int int2v __attribute__((ext_vector_type(2)));

#define B_       64
#define H_IN_    226
#define W_IN_    226
#define CIN_     32
#define H_OUT_   224
#define W_OUT_   224
#define ROWP     (W_IN_ * CIN_)      // 7232 ints per input row
#define IMGP     (H_IN_ * ROWP)
#define HB       28                  // output rows per wave; loads rows 0..29 exactly

__device__ __forceinline__ int pack4(int a, int b, int c, int d) {
    return (a & 0xff) | ((b & 0xff) << 8) | ((c & 0xff) << 16) | (d << 24);
}

__device__ __forceinline__ int dot4(int a, int b, int c) {
#if __has_builtin(__builtin_amdgcn_sdot4)
    return __builtin_amdgcn_sdot4(a, b, c, false);
#else
    return c + ((a << 24) >> 24) * ((b << 24) >> 24)
             + ((a << 16) >> 24) * ((b << 16) >> 24)
             + ((a << 8)  >> 24) * ((b << 8)  >> 24)
             + ( a        >> 24) * ( b        >> 24);
#endif
}

// Load one input row (4 consecutive w of this lane's 4-channel chunk) into raw regs.
// Rows requested are exactly 0..29 (h0 max 196 -> abs row max 225): no clamp needed.
#define LOADRAW(row) {                                                  \
    const int* p_ = base + (row) * ROWP;                                \
    r[0] = *(const int4v*)(p_);                                         \
    r[1] = *(const int4v*)(p_ + CIN_);                                  \
    r[2] = *(const int4v*)(p_ + 2 * CIN_);                              \
    r[3] = *(const int4v*)(p_ + 3 * CIN_);                              \
}

#define PACK(slot) {                                                    \
    P[slot][0] = pack4(r[0][0], r[0][1], r[0][2], r[0][3]);             \
    P[slot][1] = pack4(r[1][0], r[1][1], r[1][2], r[1][3]);             \
    P[slot][2] = pack4(r[2][0], r[2][1], r[2][2], r[2][3]);             \
    P[slot][3] = pack4(r[3][0], r[3][1], r[3][2], r[3][3]);             \
}

#define BODY(s0, s1, s2, hh) {                                          \
    int a0 = 0, a1 = 0;                                                 \
    _Pragma("unroll")                                                   \
    for (int n = 0; n < 3; ++n) {                                       \
        a0 = dot4(P[s0][n],     F[0][n], a0);                           \
        a1 = dot4(P[s0][n + 1], F[0][n], a1);                           \
        a0 = dot4(P[s1][n],     F[1][n], a0);                           \
        a1 = dot4(P[s1][n + 1], F[1][n], a1);                           \
        a0 = dot4(P[s2][n],     F[2][n], a0);                           \
        a1 = dot4(P[s2][n + 1], F[2][n], a1);                           \
    }                                                                   \
    a0 += __shfl_xor(a0, 1); a0 += __shfl_xor(a0, 2); a0 += __shfl_xor(a0, 4); \
    a1 += __shfl_xor(a1, 1); a1 += __shfl_xor(a1, 2); a1 += __shfl_xor(a1, 4); \
    if (ci == 0) {                                                      \
        long long v0 = (((long long)(a0 + bi)) * rm + rnd) >> ts;       \
        long long v1 = (((long long)(a1 + bi)) * rm + rnd) >> ts;       \
        int i0 = (int)v0 + zp, i1 = (int)v1 + zp;                       \
        i0 = min(127, max(-128, i0));                                   \
        i1 = min(127, max(-128, i1));                                   \
        int2v o_; o_[0] = i0; o_[1] = i1;                               \
        *reinterpret_cast<int2v*>(ob + (hh) * W_OUT_) = o_;             \
    }                                                                   \
}

__global__ __launch_bounds__(256, 7) void conv2d_requant_kernel(
    const int* __restrict__ in,    // (64,226,226,32)
    const int* __restrict__ filt,  // (64,3,3,32)
    const int* __restrict__ bias,  // (64,)
    const int* __restrict__ qm_p,
    const int* __restrict__ ex_p,
    const int* __restrict__ zp_p,
    int* __restrict__ out)         // (64,224,224,1) int8 stored as int32
{
    const int bx   = blockIdx.x;           // 0..1791
    const int b    = bx / 28;
    const int seg  = bx % 28;
    const int widx = seg * 4 + (threadIdx.x >> 6);  // 0..111 per batch
    const int strip = widx / 14;           // 0..7  -> h0 = strip*28
    const int wseg  = widx % 14;           // 0..13 -> w0 = wseg*16
    const int h0 = strip * HB;
    const int w0 = wseg * 16;
    const int lane = threadIdx.x & 63;
    const int wi = lane >> 3;              // 0..7 : pair of output columns
    const int ci = lane & 7;               // 0..7 : channel chunk (4 ints)

    const int qm = qm_p[0];
    const int ex = ex_p[0];
    const int zp = zp_p[0];
    const int rm = (qm < 2147418112) ? ((qm + (1 << 15)) >> 16) : 32767;
    const int ts = 15 - ex;
    const long long rnd = 1LL << (ts - 1);
    const int bi = bias[b];

    // Packed per-lane filter fragment: 3x3, 4 channels/dword
    int F[3][3];
    {
        const int* fb = filt + b * 288 + ci * 4;
#pragma unroll
        for (int m = 0; m < 3; ++m) {
#pragma unroll
            for (int n = 0; n < 3; ++n) {
                int4v t = *(const int4v*)(fb + (m * 3 + n) * CIN_);
                F[m][n] = pack4(t[0], t[1], t[2], t[3]);
            }
        }
    }

    const int* base = in + b * IMGP + h0 * ROWP + (w0 + 2 * wi) * CIN_ + ci * 4;
    int* ob = out + (b * H_OUT_ + h0) * W_OUT_ + w0 + 2 * wi;

    // 3 packed window slots + 1 raw staging buffer, loads 1 row ahead
    int P[3][4];
    int4v r[4];
    LOADRAW(0) PACK(0)
    LOADRAW(1) PACK(1)
    LOADRAW(2)

    for (int hh = 0; hh < 27; hh += 3) {
        PACK(2) LOADRAW(hh + 3) BODY(0, 1, 2, hh)
        PACK(0) LOADRAW(hh + 4) BODY(1, 2, 0, hh + 1)
        PACK(1) LOADRAW(hh + 5) BODY(2, 0, 1, hh + 2)
    }
    // Tail: row 27 (window rows 27,28,29; r holds row 29)
    PACK(2) BODY(0, 1, 2, 27)
}

extern "C" void kernel_launch(void* const* d_in, const int* in_sizes, int n_in,
                              void* d_out, int out_size, void* d_ws, size_t ws_size,
                              hipStream_t stream) {
    const int* in   = (const int*)d_in[0];
    const int* filt = (const int*)d_in[1];
    const int* bias = (const int*)d_in[2];
    const int* qm   = (const int*)d_in[3];
    const int* ex   = (const int*)d_in[4];
    const int* zp   = (const int*)d_in[5];
    int* out = (int*)d_out;

    dim3 grid(B_ * 28);   // 1792 blocks = 7 blocks/CU x 256 CU, all co-resident
    dim3 block(256);
    hipLaunchKernelGGL(conv2d_requant_kernel, grid, block, 0, stream,
                       in, filt, bias, qm, ex, zp, out);
}

// Round 6
// 102.461 us; speedup vs baseline: 1.0153x; 1.0153x over previous
//
#include <hip/hip_runtime.h>

// Conv2D per-batch 3x3x32 valid conv, int32 in (int8-range values),
// TFLite requant -> int8 (harness stores integer outputs as int32).
// B=64, H_IN=W_IN=226, CIN=32, H_OUT=W_OUT=224.
//
// v6: block(1024) = one (batch, 56-row strip); rows staged PACKED (int8) into
// a 12-row LDS ring (86.8 KB). Each input row fetched once per strip ->
// ~443 MB total HBM traffic. Per 4-row panel: T14 async-split
// (issue loads -> compute from LDS -> pack+ds_write -> barrier).
// Filter is block-uniform -> packed into (scalar) regs, dot4 MACs.

typedef int int4v __attribute__((ext_vector_type(4)));

#define B_     64
#define HB     56                 // output rows per strip (4 strips)
#define ROWU   1808               // int4-units per input row (226*32/4)
#define NROWS  58                 // input rows per strip (56+2)
#define RING   12                 // LDS ring rows (packed): 12*7232B = 86.8 KB

__device__ __forceinline__ int pack4(int a, int b, int c, int d) {
    return (a & 0xff) | ((b & 0xff) << 8) | ((c & 0xff) << 16) | (d << 24);
}

__device__ __forceinline__ int dot4(int a, int b, int c) {
#if __has_builtin(__builtin_amdgcn_sdot4)
    return __builtin_amdgcn_sdot4(a, b, c, false);
#else
    return c + ((a << 24) >> 24) * ((b << 24) >> 24)
             + ((a << 16) >> 24) * ((b << 16) >> 24)
             + ((a << 8)  >> 24) * ((b << 8)  >> 24)
             + ( a        >> 24) * ( b        >> 24);
#endif
}

__global__ __launch_bounds__(1024, 1) void conv2d_requant_kernel(
    const int4v* __restrict__ in4,   // (64,226,226,32) int32 as int4-units
    const int*  __restrict__ filt,   // (64,3,3,32)
    const int*  __restrict__ bias,   // (64,)
    const int*  __restrict__ qm_p,
    const int*  __restrict__ ex_p,
    const int*  __restrict__ zp_p,
    int* __restrict__ out)           // (64,224,224,1) int8 stored as int32
{
    __shared__ int lds[RING][ROWU];  // packed int8 rows

    const int bx    = blockIdx.x;    // 0..255
    const int b     = bx >> 2;
    const int strip = bx & 3;
    const int h0    = strip * HB;
    const int t     = threadIdx.x;   // 0..1023
    const int col   = t & 255;       // output column (active < 224)
    const int orow  = t >> 8;        // 0..3: row within panel

    // Requant constants (block-uniform -> scalar regs)
    const int qm = qm_p[0];
    const int ex = ex_p[0];
    const int zp = zp_p[0];
    const int rm = (qm < 2147418112) ? ((qm + (1 << 15)) >> 16) : 32767;
    const int ts = 15 - ex;
    const long long rnd = 1LL << (ts - 1);
    const int bi = bias[b];

    // Packed filter, block-uniform: fs[m][n][chunk] = 4 channels/dword
    int fs[3][3][8];
    {
        const int* fb = filt + b * 288;
#pragma unroll
        for (int m = 0; m < 3; ++m)
#pragma unroll
            for (int n = 0; n < 3; ++n)
#pragma unroll
                for (int c = 0; c < 8; ++c) {
                    const int* p = fb + (m * 3 + n) * 32 + 4 * c;
                    fs[m][n][c] = pack4(p[0], p[1], p[2], p[3]);
                }
    }

    const int4v* gin = in4 + (b * 226 + h0) * ROWU;
    const int outb = (b * 224 + h0) * 224;

    // ---- Prologue: stage rows 0..5 (packed) ----
#pragma unroll
    for (int r = 0; r < 6; ++r) {
        int4v v = gin[r * ROWU + t];
        lds[r][t] = pack4(v[0], v[1], v[2], v[3]);
        if (t < ROWU - 1024) {
            int4v w = gin[r * ROWU + t + 1024];
            lds[r][t + 1024] = pack4(w[0], w[1], w[2], w[3]);
        }
    }
    __syncthreads();

    int curm = 0;  // cur % RING
    for (int s = 0; s < 14; ++s) {
        const int cur = s * 4;

        // ---- T14 phase 1: issue next panel's staging loads (rows cur+6..cur+9)
        int4v g0[4], g1[4];
#pragma unroll
        for (int j = 0; j < 4; ++j) {
            const int r = cur + 6 + j;
            if (r < NROWS) {                       // uniform branch
                g0[j] = gin[r * ROWU + t];
                if (t < ROWU - 1024) g1[j] = gin[r * ROWU + t + 1024];
            }
        }

        // ---- Phase 2: compute 4 output rows (cur..cur+3) from LDS rows cur..cur+5
        if (col < 224) {
            int acc = 0;
#pragma unroll
            for (int m = 0; m < 3; ++m) {
                int sl = curm + orow + m;
                if (sl >= RING) sl -= RING;
                const int* rp = &lds[sl][0];
#pragma unroll
                for (int n = 0; n < 3; ++n) {
                    const int* cp = rp + (col + n) * 8;
                    int4v lo = *(const int4v*)cp;
                    int4v hi = *(const int4v*)(cp + 4);
                    acc = dot4(lo[0], fs[m][n][0], acc);
                    acc = dot4(lo[1], fs[m][n][1], acc);
                    acc = dot4(lo[2], fs[m][n][2], acc);
                    acc = dot4(lo[3], fs[m][n][3], acc);
                    acc = dot4(hi[0], fs[m][n][4], acc);
                    acc = dot4(hi[1], fs[m][n][5], acc);
                    acc = dot4(hi[2], fs[m][n][6], acc);
                    acc = dot4(hi[3], fs[m][n][7], acc);
                }
            }
            long long v = (((long long)(acc + bi)) * rm + rnd) >> ts;
            int q = (int)v + zp;
            q = min(127, max(-128, q));
            out[outb + (cur + orow) * 224 + col] = q;
        }

        // ---- Phase 3: pack + ds_write staged rows
#pragma unroll
        for (int j = 0; j < 4; ++j) {
            const int r = cur + 6 + j;
            if (r < NROWS) {                       // uniform branch
                int sl = curm + 6 + j;
                if (sl >= RING) sl -= RING;
                lds[sl][t] = pack4(g0[j][0], g0[j][1], g0[j][2], g0[j][3]);
                if (t < ROWU - 1024)
                    lds[sl][t + 1024] = pack4(g1[j][0], g1[j][1], g1[j][2], g1[j][3]);
            }
        }
        __syncthreads();
        curm += 4;
        if (curm >= RING) curm -= RING;
    }
}

extern "C" void kernel_launch(void* const* d_in, const int* in_sizes, int n_in,
                              void* d_out, int out_size, void* d_ws, size_t ws_size,
                              hipStream_t stream) {
    const int4v* in = (const int4v*)d_in[0];
    const int* filt = (const int*)d_in[1];
    const int* bias = (const int*)d_in[2];
    const int* qm   = (const int*)d_in[3];
    const int* ex   = (const int*)d_in[4];
    const int* zp   = (const int*)d_in[5];
    int* out = (int*)d_out;

    dim3 grid(B_ * 4);     // 256 blocks = 1 per CU (LDS-forced), perfect balance
    dim3 block(1024);
    hipLaunchKernelGGL(conv2d_requant_kernel, grid, block, 0, stream,
                       in, filt, bias, qm, ex, zp, out);
}

// Round 7
// 91.323 us; speedup vs baseline: 1.1392x; 1.1220x over previous
//
#include <hip/hip_runtime.h>

// Conv2D per-batch 3x3x32 valid conv, int32 in (int8-range values),
// TFLite requant -> int8 (harness stores integer outputs as int32).
// B=64, H_IN=W_IN=226, CIN=32, H_OUT=W_OUT=224.
//
// v7 = v4 (best: dot4-packed register window, 88.4us) + XCD-chunked block
// swizzle (T1). Halo sharers are bx+-1; chunking 224 consecutive bx per XCD
// makes halo re-reads same-XCD L2 hits. 1792 = 8*224 exactly (bijective).

typedef int int4v __attribute__((ext_vector_type(4)));
typedef int int2v __attribute__((ext_vector_type(2)));

#define B_       64
#define H_IN_    226
#define W_IN_    226
#define CIN_     32
#define H_OUT_   224
#define W_OUT_   224
#define ROWP     (W_IN_ * CIN_)      // 7232 ints per input row
#define IMGP     (H_IN_ * ROWP)
#define HB       28                  // output rows per wave
#define MAXREL   (HB + 1)            // last needed relative input row = 29
#define NXCD     8
#define NWG      1792                // 8 XCD-chunks of 224

__device__ __forceinline__ int pack4(int a, int b, int c, int d) {
    return (a & 0xff) | ((b & 0xff) << 8) | ((c & 0xff) << 16) | (d << 24);
}

__device__ __forceinline__ int dot4(int a, int b, int c) {
#if __has_builtin(__builtin_amdgcn_sdot4)
    return __builtin_amdgcn_sdot4(a, b, c, false);
#else
    return c + ((a << 24) >> 24) * ((b << 24) >> 24)
             + ((a << 16) >> 24) * ((b << 16) >> 24)
             + ((a << 8)  >> 24) * ((b << 8)  >> 24)
             + ( a        >> 24) * ( b        >> 24);
#endif
}

// Load one input row (4 consecutive w of this lane's 4-channel chunk)
#define LOADRAW(row) {                                                  \
    int rr_ = (row); if (rr_ > MAXREL) rr_ = MAXREL;                    \
    const int* p_ = base + rr_ * ROWP;                                  \
    r[0] = *(const int4v*)(p_);                                         \
    r[1] = *(const int4v*)(p_ + CIN_);                                  \
    r[2] = *(const int4v*)(p_ + 2 * CIN_);                              \
    r[3] = *(const int4v*)(p_ + 3 * CIN_);                              \
}

#define PACK(slot) {                                                    \
    P[slot][0] = pack4(r[0][0], r[0][1], r[0][2], r[0][3]);             \
    P[slot][1] = pack4(r[1][0], r[1][1], r[1][2], r[1][3]);             \
    P[slot][2] = pack4(r[2][0], r[2][1], r[2][2], r[2][3]);             \
    P[slot][3] = pack4(r[3][0], r[3][1], r[3][2], r[3][3]);             \
}

#define BODY(s0, s1, s2, hh) {                                          \
    int a0 = 0, a1 = 0;                                                 \
    _Pragma("unroll")                                                   \
    for (int n = 0; n < 3; ++n) {                                       \
        a0 = dot4(P[s0][n],     F[0][n], a0);                           \
        a1 = dot4(P[s0][n + 1], F[0][n], a1);                           \
        a0 = dot4(P[s1][n],     F[1][n], a0);                           \
        a1 = dot4(P[s1][n + 1], F[1][n], a1);                           \
        a0 = dot4(P[s2][n],     F[2][n], a0);                           \
        a1 = dot4(P[s2][n + 1], F[2][n], a1);                           \
    }                                                                   \
    a0 += __shfl_xor(a0, 1); a0 += __shfl_xor(a0, 2); a0 += __shfl_xor(a0, 4); \
    a1 += __shfl_xor(a1, 1); a1 += __shfl_xor(a1, 2); a1 += __shfl_xor(a1, 4); \
    if (ci == 0) {                                                      \
        long long v0 = (((long long)(a0 + bi)) * rm + rnd) >> ts;       \
        long long v1 = (((long long)(a1 + bi)) * rm + rnd) >> ts;       \
        int i0 = (int)v0 + zp, i1 = (int)v1 + zp;                       \
        i0 = min(127, max(-128, i0));                                   \
        i1 = min(127, max(-128, i1));                                   \
        int2v o_; o_[0] = i0; o_[1] = i1;                               \
        *reinterpret_cast<int2v*>(ob + (hh) * W_OUT_) = o_;             \
    }                                                                   \
}

#define STEP(sp, s0, s1, s2, hh, nr)  PACK(sp) LOADRAW(nr) BODY(s0, s1, s2, hh)

__global__ __launch_bounds__(256, 4) void conv2d_requant_kernel(
    const int* __restrict__ in,    // (64,226,226,32)
    const int* __restrict__ filt,  // (64,3,3,32)
    const int* __restrict__ bias,  // (64,)
    const int* __restrict__ qm_p,
    const int* __restrict__ ex_p,
    const int* __restrict__ zp_p,
    int* __restrict__ out)         // (64,224,224,1) int8 stored as int32
{
    // XCD-chunked swizzle: dispatch i -> processed block (i%8)*224 + i/8.
    // Consecutive processed blocks (halo sharers) land on the same XCD.
    const int bx   = (blockIdx.x % NXCD) * (NWG / NXCD) + blockIdx.x / NXCD;
    const int b    = bx / 28;
    const int seg  = bx % 28;
    const int widx = seg * 4 + (threadIdx.x >> 6);  // 0..111 per batch
    const int strip = widx / 14;           // 0..7  -> h0 = strip*28
    const int wseg  = widx % 14;           // 0..13 -> w0 = wseg*16
    const int h0 = strip * HB;
    const int w0 = wseg * 16;
    const int lane = threadIdx.x & 63;
    const int wi = lane >> 3;              // 0..7 : pair of output columns
    const int ci = lane & 7;               // 0..7 : channel chunk (4 ints)

    const int qm = qm_p[0];
    const int ex = ex_p[0];
    const int zp = zp_p[0];
    const int rm = (qm < 2147418112) ? ((qm + (1 << 15)) >> 16) : 32767;
    const int ts = 15 - ex;
    const long long rnd = 1LL << (ts - 1);
    const int bi = bias[b];

    // Packed per-lane filter fragment: 3x3, 4 channels/dword
    int F[3][3];
    {
        const int* fb = filt + b * 288 + ci * 4;
#pragma unroll
        for (int m = 0; m < 3; ++m) {
#pragma unroll
            for (int n = 0; n < 3; ++n) {
                int4v t = *(const int4v*)(fb + (m * 3 + n) * CIN_);
                F[m][n] = pack4(t[0], t[1], t[2], t[3]);
            }
        }
    }

    const int* base = in + b * IMGP + h0 * ROWP + (w0 + 2 * wi) * CIN_ + ci * 4;
    int* ob = out + (b * H_OUT_ + h0) * W_OUT_ + w0 + 2 * wi;

    // 4 packed window slots + 1 raw staging buffer
    int P[4][4];
    int4v r[4];
    LOADRAW(0) PACK(0)
    LOADRAW(1) PACK(1)
    LOADRAW(2) PACK(2)
    LOADRAW(3)

    for (int hh = 0; hh < HB; hh += 4) {
        STEP(3, 0, 1, 2, hh,     hh + 4)
        STEP(0, 1, 2, 3, hh + 1, hh + 5)
        STEP(1, 2, 3, 0, hh + 2, hh + 6)
        STEP(2, 3, 0, 1, hh + 3, hh + 7)
    }
}

extern "C" void kernel_launch(void* const* d_in, const int* in_sizes, int n_in,
                              void* d_out, int out_size, void* d_ws, size_t ws_size,
                              hipStream_t stream) {
    const int* in   = (const int*)d_in[0];
    const int* filt = (const int*)d_in[1];
    const int* bias = (const int*)d_in[2];
    const int* qm   = (const int*)d_in[3];
    const int* ex   = (const int*)d_in[4];
    const int* zp   = (const int*)d_in[5];
    int* out = (int*)d_out;

    dim3 grid(NWG);   // 1792 blocks = 8 XCD-chunks x 224
    dim3 block(256);
    hipLaunchKernelGGL(conv2d_requant_kernel, grid, block, 0, stream,
                       in, filt, bias, qm, ex, zp, out);
}

// Round 8
// 88.416 us; speedup vs baseline: 1.1766x; 1.0329x over previous
//
#include <hip/hip_runtime.h>

// Conv2D per-batch 3x3x32 valid conv, int32 in (values are int8-range),
// TFLite requant -> int8 (harness stores integer outputs as int32).
// B=64, H_IN=W_IN=226, CIN=32, H_OUT=W_OUT=224.
//
// FINAL (= round-4 kernel, measured best 88.4us):
// - wave = 8 w-pairs x 8 channel-chunks; dot4-packed (v_dot4_i32_i8) register
//   window (4 slots) + raw staging buffer, loads 1 row ahead.
// - Probed and rejected: deeper window (R3, -2.5%), 7-wave occupancy cap
//   (R5, -18%), LDS row-ring staging (R6, -16%), XCD swizzle (R7, -3%).
//   Halo re-reads are L2/L3-absorbed; kernel runs at ~5 TB/s unique-byte BW.

typedef int int4v __attribute__((ext_vector_type(4)));
typedef int int2v __attribute__((ext_vector_type(2)));

#define B_       64
#define H_IN_    226
#define W_IN_    226
#define CIN_     32
#define H_OUT_   224
#define W_OUT_   224
#define ROWP     (W_IN_ * CIN_)      // 7232 ints per input row
#define IMGP     (H_IN_ * ROWP)
#define HB       28                  // output rows per wave
#define MAXREL   (HB + 1)            // last needed relative input row = 29

__device__ __forceinline__ int pack4(int a, int b, int c, int d) {
    return (a & 0xff) | ((b & 0xff) << 8) | ((c & 0xff) << 16) | (d << 24);
}

__device__ __forceinline__ int dot4(int a, int b, int c) {
#if __has_builtin(__builtin_amdgcn_sdot4)
    return __builtin_amdgcn_sdot4(a, b, c, false);
#else
    return c + ((a << 24) >> 24) * ((b << 24) >> 24)
             + ((a << 16) >> 24) * ((b << 16) >> 24)
             + ((a << 8)  >> 24) * ((b << 8)  >> 24)
             + ( a        >> 24) * ( b        >> 24);
#endif
}

// Load one input row (4 consecutive w of this lane's 4-channel chunk)
#define LOADRAW(row) {                                                  \
    int rr_ = (row); if (rr_ > MAXREL) rr_ = MAXREL;                    \
    const int* p_ = base + rr_ * ROWP;                                  \
    r[0] = *(const int4v*)(p_);                                         \
    r[1] = *(const int4v*)(p_ + CIN_);                                  \
    r[2] = *(const int4v*)(p_ + 2 * CIN_);                              \
    r[3] = *(const int4v*)(p_ + 3 * CIN_);                              \
}

#define PACK(slot) {                                                    \
    P[slot][0] = pack4(r[0][0], r[0][1], r[0][2], r[0][3]);             \
    P[slot][1] = pack4(r[1][0], r[1][1], r[1][2], r[1][3]);             \
    P[slot][2] = pack4(r[2][0], r[2][1], r[2][2], r[2][3]);             \
    P[slot][3] = pack4(r[3][0], r[3][1], r[3][2], r[3][3]);             \
}

#define BODY(s0, s1, s2, hh) {                                          \
    int a0 = 0, a1 = 0;                                                 \
    _Pragma("unroll")                                                   \
    for (int n = 0; n < 3; ++n) {                                       \
        a0 = dot4(P[s0][n],     F[0][n], a0);                           \
        a1 = dot4(P[s0][n + 1], F[0][n], a1);                           \
        a0 = dot4(P[s1][n],     F[1][n], a0);                           \
        a1 = dot4(P[s1][n + 1], F[1][n], a1);                           \
        a0 = dot4(P[s2][n],     F[2][n], a0);                           \
        a1 = dot4(P[s2][n + 1], F[2][n], a1);                           \
    }                                                                   \
    a0 += __shfl_xor(a0, 1); a0 += __shfl_xor(a0, 2); a0 += __shfl_xor(a0, 4); \
    a1 += __shfl_xor(a1, 1); a1 += __shfl_xor(a1, 2); a1 += __shfl_xor(a1, 4); \
    if (ci == 0) {                                                      \
        long long v0 = (((long long)(a0 + bi)) * rm + rnd) >> ts;       \
        long long v1 = (((long long)(a1 + bi)) * rm + rnd) >> ts;       \
        int i0 = (int)v0 + zp, i1 = (int)v1 + zp;                       \
        i0 = min(127, max(-128, i0));                                   \
        i1 = min(127, max(-128, i1));                                   \
        int2v o_; o_[0] = i0; o_[1] = i1;                               \
        *reinterpret_cast<int2v*>(ob + (hh) * W_OUT_) = o_;             \
    }                                                                   \
}

#define STEP(sp, s0, s1, s2, hh, nr)  PACK(sp) LOADRAW(nr) BODY(s0, s1, s2, hh)

__global__ __launch_bounds__(256, 4) void conv2d_requant_kernel(
    const int* __restrict__ in,    // (64,226,226,32)
    const int* __restrict__ filt,  // (64,3,3,32)
    const int* __restrict__ bias,  // (64,)
    const int* __restrict__ qm_p,
    const int* __restrict__ ex_p,
    const int* __restrict__ zp_p,
    int* __restrict__ out)         // (64,224,224,1) int8 stored as int32
{
    const int bx   = blockIdx.x;           // 0..1791
    const int b    = bx / 28;
    const int seg  = bx % 28;
    const int widx = seg * 4 + (threadIdx.x >> 6);  // 0..111 per batch
    const int strip = widx / 14;           // 0..7  -> h0 = strip*28
    const int wseg  = widx % 14;           // 0..13 -> w0 = wseg*16
    const int h0 = strip * HB;
    const int w0 = wseg * 16;
    const int lane = threadIdx.x & 63;
    const int wi = lane >> 3;              // 0..7 : pair of output columns
    const int ci = lane & 7;               // 0..7 : channel chunk (4 ints)

    const int qm = qm_p[0];
    const int ex = ex_p[0];
    const int zp = zp_p[0];
    const int rm = (qm < 2147418112) ? ((qm + (1 << 15)) >> 16) : 32767;
    const int ts = 15 - ex;
    const long long rnd = 1LL << (ts - 1);
    const int bi = bias[b];

    // Packed per-lane filter fragment: 3x3, 4 channels/dword
    int F[3][3];
    {
        const int* fb = filt + b * 288 + ci * 4;
#pragma unroll
        for (int m = 0; m < 3; ++m) {
#pragma unroll
            for (int n = 0; n < 3; ++n) {
                int4v t = *(const int4v*)(fb + (m * 3 + n) * CIN_);
                F[m][n] = pack4(t[0], t[1], t[2], t[3]);
            }
        }
    }

    const int* base = in + b * IMGP + h0 * ROWP + (w0 + 2 * wi) * CIN_ + ci * 4;
    int* ob = out + (b * H_OUT_ + h0) * W_OUT_ + w0 + 2 * wi;

    // 4 packed window slots + 1 raw staging buffer
    int P[4][4];
    int4v r[4];
    LOADRAW(0) PACK(0)
    LOADRAW(1) PACK(1)
    LOADRAW(2) PACK(2)
    LOADRAW(3)

    for (int hh = 0; hh < HB; hh += 4) {
        STEP(3, 0, 1, 2, hh,     hh + 4)
        STEP(0, 1, 2, 3, hh + 1, hh + 5)
        STEP(1, 2, 3, 0, hh + 2, hh + 6)
        STEP(2, 3, 0, 1, hh + 3, hh + 7)
    }
}

extern "C" void kernel_launch(void* const* d_in, const int* in_sizes, int n_in,
                              void* d_out, int out_size, void* d_ws, size_t ws_size,
                              hipStream_t stream) {
    const int* in   = (const int*)d_in[0];
    const int* filt = (const int*)d_in[1];
    const int* bias = (const int*)d_in[2];
    const int* qm   = (const int*)d_in[3];
    const int* ex   = (const int*)d_in[4];
    const int* zp   = (const int*)d_in[5];
    int* out = (int*)d_out;

    dim3 grid(B_ * 28);   // 64 batches x 28 blocks (8 strips x 14 wsegs)
    dim3 block(256);
    hipLaunchKernelGGL(conv2d_requant_kernel, grid, block, 0, stream,
                       in, filt, bias, qm, ex, zp, out);
}

// Round 9
// 87.621 us; speedup vs baseline: 1.1873x; 1.0091x over previous
//
#include <hip/hip_runtime.h>

// Conv2D per-batch 3x3x32 valid conv, int32 in (values are int8-range),
// TFLite requant -> int8 (harness stores integer outputs as int32).
// B=64, H_IN=W_IN=226, CIN=32, H_OUT=W_OUT=224.
//
// v9 = v4 (best, 88.4us) + depth-2 staging: TWO alternating raw buffers
// (rA even steps, rB odd steps) -> load->consume gap of 2 STEPs, 8 loads
// in flight per wave (~880xN cyc coverage vs ~550 blended latency).

typedef int int4v __attribute__((ext_vector_type(4)));
typedef int int2v __attribute__((ext_vector_type(2)));

#define B_       64
#define H_IN_    226
#define W_IN_    226
#define CIN_     32
#define H_OUT_   224
#define W_OUT_   224
#define ROWP     (W_IN_ * CIN_)      // 7232 ints per input row
#define IMGP     (H_IN_ * ROWP)
#define HB       28                  // output rows per wave
#define MAXREL   (HB + 1)            // last needed relative input row = 29

__device__ __forceinline__ int pack4(int a, int b, int c, int d) {
    return (a & 0xff) | ((b & 0xff) << 8) | ((c & 0xff) << 16) | (d << 24);
}

__device__ __forceinline__ int dot4(int a, int b, int c) {
#if __has_builtin(__builtin_amdgcn_sdot4)
    return __builtin_amdgcn_sdot4(a, b, c, false);
#else
    return c + ((a << 24) >> 24) * ((b << 24) >> 24)
             + ((a << 16) >> 24) * ((b << 16) >> 24)
             + ((a << 8)  >> 24) * ((b << 8)  >> 24)
             + ( a        >> 24) * ( b        >> 24);
#endif
}

// Load one input row into raw buffer rb (4 consecutive w of this lane's chunk)
#define LOADRAW(rb, row) {                                              \
    int rr_ = (row); if (rr_ > MAXREL) rr_ = MAXREL;                    \
    const int* p_ = base + rr_ * ROWP;                                  \
    rb[0] = *(const int4v*)(p_);                                        \
    rb[1] = *(const int4v*)(p_ + CIN_);                                 \
    rb[2] = *(const int4v*)(p_ + 2 * CIN_);                             \
    rb[3] = *(const int4v*)(p_ + 3 * CIN_);                             \
}

#define PACKR(rb, slot) {                                               \
    P[slot][0] = pack4(rb[0][0], rb[0][1], rb[0][2], rb[0][3]);         \
    P[slot][1] = pack4(rb[1][0], rb[1][1], rb[1][2], rb[1][3]);         \
    P[slot][2] = pack4(rb[2][0], rb[2][1], rb[2][2], rb[2][3]);         \
    P[slot][3] = pack4(rb[3][0], rb[3][1], rb[3][2], rb[3][3]);         \
}

#define BODY(s0, s1, s2, hh) {                                          \
    int a0 = 0, a1 = 0;                                                 \
    _Pragma("unroll")                                                   \
    for (int n = 0; n < 3; ++n) {                                       \
        a0 = dot4(P[s0][n],     F[0][n], a0);                           \
        a1 = dot4(P[s0][n + 1], F[0][n], a1);                           \
        a0 = dot4(P[s1][n],     F[1][n], a0);                           \
        a1 = dot4(P[s1][n + 1], F[1][n], a1);                           \
        a0 = dot4(P[s2][n],     F[2][n], a0);                           \
        a1 = dot4(P[s2][n + 1], F[2][n], a1);                           \
    }                                                                   \
    a0 += __shfl_xor(a0, 1); a0 += __shfl_xor(a0, 2); a0 += __shfl_xor(a0, 4); \
    a1 += __shfl_xor(a1, 1); a1 += __shfl_xor(a1, 2); a1 += __shfl_xor(a1, 4); \
    if (ci == 0) {                                                      \
        long long v0 = (((long long)(a0 + bi)) * rm + rnd) >> ts;       \
        long long v1 = (((long long)(a1 + bi)) * rm + rnd) >> ts;       \
        int i0 = (int)v0 + zp, i1 = (int)v1 + zp;                       \
        i0 = min(127, max(-128, i0));                                   \
        i1 = min(127, max(-128, i1));                                   \
        int2v o_; o_[0] = i0; o_[1] = i1;                               \
        *reinterpret_cast<int2v*>(ob + (hh) * W_OUT_) = o_;             \
    }                                                                   \
}

// Depth-2 step: pack row hh+2 (loaded 2 steps ago into rb), issue row hh+4
// into the same (now free) buffer, compute row hh.
#define STEP2(rb, sp, s0, s1, s2, hh)                                   \
    PACKR(rb, sp) LOADRAW(rb, (hh) + 4) BODY(s0, s1, s2, hh)

__global__ __launch_bounds__(256, 4) void conv2d_requant_kernel(
    const int* __restrict__ in,    // (64,226,226,32)
    const int* __restrict__ filt,  // (64,3,3,32)
    const int* __restrict__ bias,  // (64,)
    const int* __restrict__ qm_p,
    const int* __restrict__ ex_p,
    const int* __restrict__ zp_p,
    int* __restrict__ out)         // (64,224,224,1) int8 stored as int32
{
    const int bx   = blockIdx.x;           // 0..1791
    const int b    = bx / 28;
    const int seg  = bx % 28;
    const int widx = seg * 4 + (threadIdx.x >> 6);  // 0..111 per batch
    const int strip = widx / 14;           // 0..7  -> h0 = strip*28
    const int wseg  = widx % 14;           // 0..13 -> w0 = wseg*16
    const int h0 = strip * HB;
    const int w0 = wseg * 16;
    const int lane = threadIdx.x & 63;
    const int wi = lane >> 3;              // 0..7 : pair of output columns
    const int ci = lane & 7;               // 0..7 : channel chunk (4 ints)

    const int qm = qm_p[0];
    const int ex = ex_p[0];
    const int zp = zp_p[0];
    const int rm = (qm < 2147418112) ? ((qm + (1 << 15)) >> 16) : 32767;
    const int ts = 15 - ex;
    const long long rnd = 1LL << (ts - 1);
    const int bi = bias[b];

    // Packed per-lane filter fragment: 3x3, 4 channels/dword
    int F[3][3];
    {
        const int* fb = filt + b * 288 + ci * 4;
#pragma unroll
        for (int m = 0; m < 3; ++m) {
#pragma unroll
            for (int n = 0; n < 3; ++n) {
                int4v t = *(const int4v*)(fb + (m * 3 + n) * CIN_);
                F[m][n] = pack4(t[0], t[1], t[2], t[3]);
            }
        }
    }

    const int* base = in + b * IMGP + h0 * ROWP + (w0 + 2 * wi) * CIN_ + ci * 4;
    int* ob = out + (b * H_OUT_ + h0) * W_OUT_ + w0 + 2 * wi;

    // 4 packed window slots + 2 alternating raw staging buffers
    int P[4][4];
    int4v rA[4], rB[4];

    // Prologue: rows 0,1 in flight together; then 2,3 behind their packs.
    LOADRAW(rA, 0) LOADRAW(rB, 1)
    PACKR(rA, 0)   LOADRAW(rA, 2)
    PACKR(rB, 1)   LOADRAW(rB, 3)

    for (int hh = 0; hh < HB; hh += 4) {
        STEP2(rA, 2, 0, 1, 2, hh)        // pack row hh+2, load hh+4, body hh
        STEP2(rB, 3, 1, 2, 3, hh + 1)    // pack row hh+3, load hh+5, body hh+1
        STEP2(rA, 0, 2, 3, 0, hh + 2)    // pack row hh+4, load hh+6, body hh+2
        STEP2(rB, 1, 3, 0, 1, hh + 3)    // pack row hh+5, load hh+7, body hh+3
    }
}

extern "C" void kernel_launch(void* const* d_in, const int* in_sizes, int n_in,
                              void* d_out, int out_size, void* d_ws, size_t ws_size,
                              hipStream_t stream) {
    const int* in   = (const int*)d_in[0];
    const int* filt = (const int*)d_in[1];
    const int* bias = (const int*)d_in[2];
    const int* qm   = (const int*)d_in[3];
    const int* ex   = (const int*)d_in[4];
    const int* zp   = (const int*)d_in[5];
    int* out = (int*)d_out;

    dim3 grid(B_ * 28);   // 64 batches x 28 blocks (8 strips x 14 wsegs)
    dim3 block(256);
    hipLaunchKernelGGL(conv2d_requant_kernel, grid, block, 0, stream,
                       in, filt, bias, qm, ex, zp, out);
}